// Round 1
// baseline (33.444 us; speedup 1.0000x reference)
//
#include <hip/hip_runtime.h>

#define B_   4
#define K_   8
#define N_   4096       // H*W
#define DV_  32
#define NC_  256        // 2^K_

// ---------------- ws layout ----------------
// [0..16)      int flags[4]      : flags[0] = mask layout (0=i32,1=f32,2=u8,3=i64)
// [16..32)     int evid[B_]      : evidence count per batch
// [32..4128)   int cnt[B_*256]   : evidence-code histogram per batch
// [4224..69760) int codes[B_*N_]
// [69760..200832) float ctx[B_*256*32]
#define WS_OFF_EVID   16
#define WS_OFF_CNT    32
#define WS_OFF_CODES  4224
#define WS_OFF_CTX    69760
#define WS_NEEDED     200832

__device__ __forceinline__ int read_mask(const void* m, int layout, int idx) {
    if (layout == 0) return ((const int*)m)[idx] != 0;
    if (layout == 1) return ((const float*)m)[idx] != 0.0f;
    if (layout == 3) return ((const int*)m)[2 * idx] != 0;  // int64 little-endian low word
    return ((const unsigned char*)m)[idx] != 0;
}

// K0: detect mask element layout + zero the counters.
// Reads exactly 16384 bytes of the mask buffer — safe under every candidate
// layout (u8 buffer is exactly 16384 bytes).
__global__ void k0_detect_zero(const void* mask, int* flags, int* cnt, int* evid) {
    __shared__ int ok[3];  // 0:i32, 1:f32, 2:i64
    int tid = threadIdx.x;
    if (tid < 3) ok[tid] = 1;
    __syncthreads();
    const unsigned int* mi = (const unsigned int*)mask;
    int li32 = 1, lf32 = 1, li64 = 1;
    for (int i = tid; i < 4096; i += 256) {
        unsigned int v = mi[i];
        li32 &= (v <= 1u);
        lf32 &= (v == 0u || v == 0x3F800000u);
        li64 &= ((i & 1) ? (v == 0u) : (v <= 1u));
    }
    if (!li32) atomicAnd(&ok[0], 0);
    if (!lf32) atomicAnd(&ok[1], 0);
    if (!li64) atomicAnd(&ok[2], 0);
    for (int i = tid; i < B_ * NC_; i += 256) cnt[i] = 0;
    if (tid < B_) evid[tid] = 0;
    __syncthreads();
    if (tid == 0) {
        // priority: i64 (implies i32 pattern), then i32, then f32, else u8
        flags[0] = ok[2] ? 3 : (ok[0] ? 0 : (ok[1] ? 1 : 2));
    }
}

// K1: bit-pack codes + evidence-gated histogram. grid = B_*16, block = 256.
__global__ void k1_codes_hist(const float* __restrict__ z, const void* mask,
                              const int* __restrict__ flags,
                              int* __restrict__ codes, int* cnt, int* evid) {
    __shared__ int h[NC_];
    __shared__ int evid_sh;
    int tid = threadIdx.x;
    int b = blockIdx.x >> 4;
    int n = ((blockIdx.x & 15) << 8) + tid;
    h[tid] = 0;
    if (tid == 0) evid_sh = 0;
    __syncthreads();
    const float* zb = z + (size_t)b * K_ * N_ + n;
    int code = 0;
#pragma unroll
    for (int j = 0; j < K_; ++j) code |= (zb[j * N_] > 0.5f ? 1 : 0) << j;
    codes[b * N_ + n] = code;
    int layout = flags[0];
    if (read_mask(mask, layout, b * N_ + n)) {
        atomicAdd(&h[code], 1);
        atomicAdd(&evid_sh, 1);
    }
    __syncthreads();
    if (h[tid]) atomicAdd(&cnt[b * NC_ + tid], h[tid]);
    if (tid == 0 && evid_sh) atomicAdd(&evid[b], evid_sh);
}

// K2: per-(query-code, d) context. grid = B_*8, block = 1024 (32 q x 32 d).
__global__ void __launch_bounds__(1024)
k2_ctx(const int* __restrict__ cnt, const int* __restrict__ evid,
       const float* __restrict__ V, const float* __restrict__ mask_value,
       const float* __restrict__ temperature, float* __restrict__ ctx) {
    __shared__ float Vs[NC_ * DV_];   // 32 KB
    __shared__ float csf[NC_];
    int tid = threadIdx.x;
    int b = blockIdx.x >> 3;
    int q = ((blockIdx.x & 7) << 5) + (tid >> 5);
    int d = tid & 31;
    if (tid < NC_) csf[tid] = (float)cnt[b * NC_ + tid];
    for (int i = tid; i < NC_ * DV_; i += 1024) Vs[i] = V[i];
    __syncthreads();
    float* outp = ctx + (size_t)b * NC_ * DV_ + q * DV_ + d;
    if (evid[b] == 0) { *outp = mask_value[d]; return; }
    float temp = fmaxf(temperature[0], 0.1f);
    float rinv = -1.0f / temp;
    float num = 0.0f, den = 0.0f;
#pragma unroll 4
    for (int c = 0; c < NC_; ++c) {
        float cc = csf[c];                               // LDS broadcast (uniform c)
        float w = cc * __expf((float)__popc(q ^ c) * rinv);
        den += w;
        num = fmaf(w, Vs[c * DV_ + d], num);
    }
    *outp = num / den;
}

// K3: gather + transpose write. grid = B_*16, block = 256.
__global__ void k3_out(const int* __restrict__ codes, const float* __restrict__ ctx,
                       float* __restrict__ out) {
    __shared__ float ctxL[NC_ * 33];  // +1 pad: bank = (c+d)%32, conflict-free gather
    int tid = threadIdx.x;
    int b = blockIdx.x >> 4;
    int n0 = (blockIdx.x & 15) << 8;
    const float* cb = ctx + (size_t)b * NC_ * DV_;
    for (int i = tid; i < NC_ * DV_; i += 256) {
        int c = i >> 5, d = i & 31;
        ctxL[c * 33 + d] = cb[i];
    }
    int code = codes[b * N_ + n0 + tid];
    __syncthreads();
    float* ob = out + (size_t)b * DV_ * N_ + n0 + tid;
#pragma unroll
    for (int d = 0; d < DV_; ++d) ob[d * N_] = ctxL[code * 33 + d];
}

// Fallback: fully fused, zero workspace. grid = B_, block = 1024.
__global__ void __launch_bounds__(1024)
fused_all(const float* __restrict__ z, const void* mask, const float* __restrict__ V,
          const float* __restrict__ mask_value, const float* __restrict__ temperature,
          float* __restrict__ out) {
    __shared__ unsigned short codesL[N_];   // 8 KB
    __shared__ float csf[NC_];
    __shared__ int cs[NC_];
    __shared__ float ctxL[NC_ * 33];        // ~33 KB
    __shared__ int ok[3];
    __shared__ int evid_sh;
    int tid = threadIdx.x;
    int b = blockIdx.x;
    if (tid < 3) ok[tid] = 1;
    if (tid == 0) evid_sh = 0;
    if (tid < NC_) cs[tid] = 0;
    __syncthreads();
    {
        const unsigned int* mi = (const unsigned int*)mask;
        int li32 = 1, lf32 = 1, li64 = 1;
        for (int i = tid; i < 4096; i += 1024) {
            unsigned int v = mi[i];
            li32 &= (v <= 1u);
            lf32 &= (v == 0u || v == 0x3F800000u);
            li64 &= ((i & 1) ? (v == 0u) : (v <= 1u));
        }
        if (!li32) atomicAnd(&ok[0], 0);
        if (!lf32) atomicAnd(&ok[1], 0);
        if (!li64) atomicAnd(&ok[2], 0);
    }
    __syncthreads();
    int layout = ok[2] ? 3 : (ok[0] ? 0 : (ok[1] ? 1 : 2));
    for (int i = tid; i < N_; i += 1024) {
        const float* zb = z + (size_t)b * K_ * N_ + i;
        int code = 0;
#pragma unroll
        for (int j = 0; j < K_; ++j) code |= (zb[j * N_] > 0.5f ? 1 : 0) << j;
        codesL[i] = (unsigned short)code;
        if (read_mask(mask, layout, b * N_ + i)) {
            atomicAdd(&cs[code], 1);
            atomicAdd(&evid_sh, 1);
        }
    }
    __syncthreads();
    if (tid < NC_) csf[tid] = (float)cs[tid];
    __syncthreads();
    int evid = evid_sh;
    float temp = fmaxf(temperature[0], 0.1f);
    float rinv = -1.0f / temp;
    int d = tid & 31;
    for (int qi = 0; qi < 8; ++qi) {
        int q = (qi << 5) + (tid >> 5);
        float num = 0.0f, den = 0.0f;
        for (int c = 0; c < NC_; ++c) {
            float cc = csf[c];
            float w = cc * __expf((float)__popc(q ^ c) * rinv);
            den += w;
            num = fmaf(w, V[c * DV_ + d], num);
        }
        ctxL[q * 33 + d] = (evid == 0) ? mask_value[d] : num / den;
    }
    __syncthreads();
    for (int idx = tid; idx < DV_ * N_; idx += 1024) {
        int dd = idx >> 12;
        int n = idx & (N_ - 1);
        out[(size_t)b * DV_ * N_ + idx] = ctxL[codesL[n] * 33 + dd];
    }
}

extern "C" void kernel_launch(void* const* d_in, const int* in_sizes, int n_in,
                              void* d_out, int out_size, void* d_ws, size_t ws_size,
                              hipStream_t stream) {
    const float* z    = (const float*)d_in[0];
    const void*  mask = d_in[1];
    const float* V    = (const float*)d_in[2];
    const float* mv   = (const float*)d_in[3];
    const float* temp = (const float*)d_in[4];
    float* out = (float*)d_out;

    if (ws_size >= (size_t)WS_NEEDED) {
        char* ws = (char*)d_ws;
        int*   flags = (int*)ws;
        int*   evid  = (int*)(ws + WS_OFF_EVID);
        int*   cnt   = (int*)(ws + WS_OFF_CNT);
        int*   codes = (int*)(ws + WS_OFF_CODES);
        float* ctx   = (float*)(ws + WS_OFF_CTX);
        k0_detect_zero<<<1, 256, 0, stream>>>(mask, flags, cnt, evid);
        k1_codes_hist<<<B_ * 16, 256, 0, stream>>>(z, mask, flags, codes, cnt, evid);
        k2_ctx<<<B_ * 8, 1024, 0, stream>>>(cnt, evid, V, mv, temp, ctx);
        k3_out<<<B_ * 16, 256, 0, stream>>>(codes, ctx, out);
    } else {
        fused_all<<<B_, 1024, 0, stream>>>(z, mask, V, mv, temp, out);
    }
}

// Round 2
// 29.841 us; speedup vs baseline: 1.1207x; 1.1207x over previous
//
#include <hip/hip_runtime.h>

#define B_   4
#define K_   8
#define N_   4096       // H*W
#define DV_  32
#define NC_  256        // 2^K_

// ---------------- ws layout ----------------
// [0, 65536)      int part_hist[64][256]  (one private histogram per k1 block)
// [65536, 81920)  uchar codes[B_*N_]
#define WS_OFF_CODES 65536
#define WS_NEEDED    81920

__device__ __forceinline__ int read_mask(const void* m, int layout, int idx) {
    if (layout == 0) return ((const int*)m)[idx] != 0;
    if (layout == 1) return ((const float*)m)[idx] != 0.0f;
    if (layout == 3) return ((const int*)m)[2 * idx] != 0;  // int64 LE low word
    return ((const unsigned char*)m)[idx] != 0;
}

// Every block scans the same leading 16 KB window (safe under all candidate
// layouts; u8 buffer is exactly 16 KB) -> deterministic, identical verdict.
__device__ __forceinline__ int detect_layout(const void* mask, int tid) {
    __shared__ int ok[3];  // 0:i32, 1:f32, 2:i64
    if (tid < 3) ok[tid] = 1;
    __syncthreads();
    const unsigned int* mi = (const unsigned int*)mask;
    int li32 = 1, lf32 = 1, li64 = 1;
    for (int i = tid; i < 4096; i += 256) {
        unsigned int v = mi[i];
        li32 &= (v <= 1u);
        lf32 &= (v == 0u || v == 0x3F800000u);
        li64 &= ((i & 1) ? (v == 0u) : (v <= 1u));
    }
    if (!li32) atomicAnd(&ok[0], 0);
    if (!lf32) atomicAnd(&ok[1], 0);
    if (!li64) atomicAnd(&ok[2], 0);
    __syncthreads();
    return ok[2] ? 3 : (ok[0] ? 0 : (ok[1] ? 1 : 2));
}

// K1: layout detect + bit-pack codes + per-block evidence histogram.
// grid = B_*16, block = 256. No global atomics, no pre-zeroing needed.
__global__ void k1_codes_hist(const float* __restrict__ z, const void* mask,
                              int* __restrict__ part, unsigned char* __restrict__ codes) {
    __shared__ int hist[NC_];
    int tid = threadIdx.x;
    int b = blockIdx.x >> 4;
    int n = ((blockIdx.x & 15) << 8) + tid;
    int layout = detect_layout(mask, tid);
    hist[tid] = 0;
    __syncthreads();
    const float* zb = z + (size_t)b * K_ * N_ + n;
    int code = 0;
#pragma unroll
    for (int j = 0; j < K_; ++j) code |= (zb[j * N_] > 0.5f ? 1 : 0) << j;
    codes[b * N_ + n] = (unsigned char)code;
    if (read_mask(mask, layout, b * N_ + n)) atomicAdd(&hist[code], 1);
    __syncthreads();
    part[blockIdx.x * NC_ + tid] = hist[tid];
}

// K2: reduce histograms -> Kronecker-butterfly ctx -> gather + transposed write.
// W[q,c] = t^popc(q^c) = [[1,t],[t,1]]^{(x)8}; 8 butterfly stages over 256x33
// (32 V-columns + 1 denominator column). grid = B_*16, block = 256.
__global__ void __launch_bounds__(256)
k2_ctx_gather(const int* __restrict__ part, const unsigned char* __restrict__ codes,
              const float* __restrict__ V, const float* __restrict__ mv,
              const float* __restrict__ temperature, float* __restrict__ out) {
    __shared__ float X[NC_ * 33];   // ~33 KB, row stride 33 (odd -> conflict-light)
    __shared__ float CS[NC_];
    __shared__ int red[4];
    int tid = threadIdx.x;
    int b = blockIdx.x >> 4;
    int n0 = (blockIdx.x & 15) << 8;

    // sum this batch's 16 private histograms
    int c = 0;
#pragma unroll
    for (int j = 0; j < 16; ++j) c += part[(b * 16 + j) * NC_ + tid];
    CS[tid] = (float)c;

    // evidence count = sum of histogram (wave shuffle + LDS across 4 waves)
    int s = c;
#pragma unroll
    for (int off = 32; off; off >>= 1) s += __shfl_down(s, off);
    if ((tid & 63) == 0) red[tid >> 6] = s;
    __syncthreads();
    int evid = red[0] + red[1] + red[2] + red[3];

    float temp = fmaxf(temperature[0], 0.1f);
    float t = __expf(-1.0f / temp);

    // init: X[c][0..31] = cnt[c]*V[c][d], X[c][32] = cnt[c]
    for (int i = tid; i < NC_ * 33; i += 256) {
        int cc = i / 33, col = i - cc * 33;
        float cf = CS[cc];
        X[i] = (col < DV_) ? cf * V[cc * DV_ + col] : cf;
    }
    __syncthreads();

    // 8 butterfly stages: x0' = x0 + t*x1 ; x1' = t*x0 + x1
#pragma unroll
    for (int stg = 0; stg < 8; ++stg) {
        int bit = 1 << stg;
        for (int p = tid; p < 128 * 33; p += 256) {
            int pi = p / 33, col = p - pi * 33;
            int c0 = ((pi >> stg) << (stg + 1)) | (pi & (bit - 1));
            int i0 = c0 * 33 + col, i1 = i0 + bit * 33;
            float x0 = X[i0], x1 = X[i1];
            X[i0] = fmaf(t, x1, x0);
            X[i1] = fmaf(t, x0, x1);
        }
        __syncthreads();
    }

    // gather by code, write transposed (out[b][d][n], n contiguous per wave)
    int code = codes[b * N_ + n0 + tid];
    float* ob = out + (size_t)b * DV_ * N_ + n0 + tid;
    if (evid == 0) {
#pragma unroll
        for (int d = 0; d < DV_; ++d) ob[d * N_] = mv[d];
    } else {
        float rden = 1.0f / X[code * 33 + DV_];
#pragma unroll
        for (int d = 0; d < DV_; ++d) ob[d * N_] = X[code * 33 + d] * rden;
    }
}

// Fallback: fully fused, zero workspace. grid = B_, block = 1024.
__global__ void __launch_bounds__(1024)
fused_all(const float* __restrict__ z, const void* mask, const float* __restrict__ V,
          const float* __restrict__ mask_value, const float* __restrict__ temperature,
          float* __restrict__ out) {
    __shared__ unsigned short codesL[N_];
    __shared__ float csf[NC_];
    __shared__ int cs[NC_];
    __shared__ float ctxL[NC_ * 33];
    __shared__ int ok[3];
    __shared__ int evid_sh;
    int tid = threadIdx.x;
    int b = blockIdx.x;
    if (tid < 3) ok[tid] = 1;
    if (tid == 0) evid_sh = 0;
    if (tid < NC_) cs[tid] = 0;
    __syncthreads();
    {
        const unsigned int* mi = (const unsigned int*)mask;
        int li32 = 1, lf32 = 1, li64 = 1;
        for (int i = tid; i < 4096; i += 1024) {
            unsigned int v = mi[i];
            li32 &= (v <= 1u);
            lf32 &= (v == 0u || v == 0x3F800000u);
            li64 &= ((i & 1) ? (v == 0u) : (v <= 1u));
        }
        if (!li32) atomicAnd(&ok[0], 0);
        if (!lf32) atomicAnd(&ok[1], 0);
        if (!li64) atomicAnd(&ok[2], 0);
    }
    __syncthreads();
    int layout = ok[2] ? 3 : (ok[0] ? 0 : (ok[1] ? 1 : 2));
    for (int i = tid; i < N_; i += 1024) {
        const float* zb = z + (size_t)b * K_ * N_ + i;
        int code = 0;
#pragma unroll
        for (int j = 0; j < K_; ++j) code |= (zb[j * N_] > 0.5f ? 1 : 0) << j;
        codesL[i] = (unsigned short)code;
        if (read_mask(mask, layout, b * N_ + i)) {
            atomicAdd(&cs[code], 1);
            atomicAdd(&evid_sh, 1);
        }
    }
    __syncthreads();
    if (tid < NC_) csf[tid] = (float)cs[tid];
    __syncthreads();
    int evid = evid_sh;
    float temp = fmaxf(temperature[0], 0.1f);
    float rinv = -1.0f / temp;
    int d = tid & 31;
    for (int qi = 0; qi < 8; ++qi) {
        int q = (qi << 5) + (tid >> 5);
        float num = 0.0f, den = 0.0f;
        for (int c = 0; c < NC_; ++c) {
            float cc = csf[c];
            float w = cc * __expf((float)__popc(q ^ c) * rinv);
            den += w;
            num = fmaf(w, V[c * DV_ + d], num);
        }
        ctxL[q * 33 + d] = (evid == 0) ? mask_value[d] : num / den;
    }
    __syncthreads();
    for (int idx = tid; idx < DV_ * N_; idx += 1024) {
        int dd = idx >> 12;
        int n = idx & (N_ - 1);
        out[(size_t)b * DV_ * N_ + idx] = ctxL[codesL[n] * 33 + dd];
    }
}

extern "C" void kernel_launch(void* const* d_in, const int* in_sizes, int n_in,
                              void* d_out, int out_size, void* d_ws, size_t ws_size,
                              hipStream_t stream) {
    const float* z    = (const float*)d_in[0];
    const void*  mask = d_in[1];
    const float* V    = (const float*)d_in[2];
    const float* mv   = (const float*)d_in[3];
    const float* temp = (const float*)d_in[4];
    float* out = (float*)d_out;

    if (ws_size >= (size_t)WS_NEEDED) {
        char* ws = (char*)d_ws;
        int*           part  = (int*)ws;
        unsigned char* codes = (unsigned char*)(ws + WS_OFF_CODES);
        k1_codes_hist<<<B_ * 16, 256, 0, stream>>>(z, mask, part, codes);
        k2_ctx_gather<<<B_ * 16, 256, 0, stream>>>(part, codes, V, mv, temp, out);
    } else {
        fused_all<<<B_, 1024, 0, stream>>>(z, mask, V, mv, temp, out);
    }
}